// Round 10
// baseline (344.646 us; speedup 1.0000x reference)
//
#include <hip/hip_runtime.h>
#include <hip/hip_bf16.h>
#include <cstdint>

#define B_ 16
#define N_ 1024
#define D_ 256
#define H_ 128

typedef unsigned short u16;
typedef __attribute__((ext_vector_type(8))) short bf16x8;
typedef __attribute__((ext_vector_type(4))) float f32x4;

__device__ __forceinline__ u16 f2bf(float f) {
    union { float f; uint32_t u; } v; v.f = f;
    return (u16)((v.u + 0x7FFFu + ((v.u >> 16) & 1u)) >> 16);  // RNE
}
__device__ __forceinline__ float bf2f(u16 h) {
    union { uint32_t u; float f; } v; v.u = ((uint32_t)h) << 16;
    return v.f;
}

typedef __attribute__((address_space(3))) void lds_void;
typedef const __attribute__((address_space(1))) void g_void;

__device__ __forceinline__ void gl_lds16(const void* g, void* l) {
    __builtin_amdgcn_global_load_lds((g_void*)g, (lds_void*)l, 16, 0, 0);
}

__device__ __forceinline__ void vm_wait6() { asm volatile("s_waitcnt vmcnt(6)" ::: "memory"); }
__device__ __forceinline__ void vm_wait4() { asm volatile("s_waitcnt vmcnt(4)" ::: "memory"); }
__device__ __forceinline__ void vm_wait3() { asm volatile("s_waitcnt vmcnt(3)" ::: "memory"); }
__device__ __forceinline__ void vm_wait0() { asm volatile("s_waitcnt vmcnt(0)" ::: "memory"); }
__device__ __forceinline__ void lgkm0()   { asm volatile("s_waitcnt lgkmcnt(0)" ::: "memory"); }
__device__ __forceinline__ void schedb()  { __builtin_amdgcn_sched_barrier(0); }

// ---------------------------------------------------------------------------
// K1: fp32 adjacencies -> bf16 (normal + transposed). 64x64 tiles, conflict-
// free swizzle (slot = g ^ ((r&7)^((r>>3)&7)); measured 0 conflicts r8).
// grid (16, 16, B*2), block 256.
__global__ __launch_bounds__(256) void k_conv_adj(
    const float* __restrict__ dep, const float* __restrict__ lat,
    u16* __restrict__ depb, u16* __restrict__ latb,
    u16* __restrict__ depTb, u16* __restrict__ latTb)
{
    __shared__ u16 tile[64][64];
    const int bz = blockIdx.z;
    const int b = bz >> 1;
    const float* src = (bz & 1) ? lat : dep;
    u16* dstN = (bz & 1) ? latb : depb;
    u16* dstT = (bz & 1) ? latTb : depTb;
    const int r0 = blockIdx.y * 64, c0 = blockIdx.x * 64;
    const int t = threadIdx.x;
    const int r = t >> 2, cg = (t & 3) * 16;

    const float* srow = src + ((size_t)b * N_ + r0 + r) * N_ + c0 + cg;
    bf16x8 lo, hi;
    {
        const float4 v0 = *(const float4*)(srow);
        const float4 v1 = *(const float4*)(srow + 4);
        const float4 v2 = *(const float4*)(srow + 8);
        const float4 v3 = *(const float4*)(srow + 12);
        lo[0] = (short)f2bf(v0.x); lo[1] = (short)f2bf(v0.y); lo[2] = (short)f2bf(v0.z); lo[3] = (short)f2bf(v0.w);
        lo[4] = (short)f2bf(v1.x); lo[5] = (short)f2bf(v1.y); lo[6] = (short)f2bf(v1.z); lo[7] = (short)f2bf(v1.w);
        hi[0] = (short)f2bf(v2.x); hi[1] = (short)f2bf(v2.y); hi[2] = (short)f2bf(v2.z); hi[3] = (short)f2bf(v2.w);
        hi[4] = (short)f2bf(v3.x); hi[5] = (short)f2bf(v3.y); hi[6] = (short)f2bf(v3.z); hi[7] = (short)f2bf(v3.w);
    }
    u16* nrow = dstN + ((size_t)b * N_ + r0 + r) * N_ + c0 + cg;
    *(bf16x8*)nrow = lo;
    *(bf16x8*)(nrow + 8) = hi;

    const int g0 = (t & 3) * 2;
    const int s = (r & 7) ^ ((r >> 3) & 7);
    *(bf16x8*)(&tile[r][((g0    ) ^ s) * 8]) = lo;
    *(bf16x8*)(&tile[r][((g0 + 1) ^ s) * 8]) = hi;
    __syncthreads();

    const int sc = t >> 2, rg2 = (t & 3) * 16;
    bf16x8 o0, o1;
    #pragma unroll
    for (int i = 0; i < 8; ++i) {
        const int R = rg2 + i;
        const int sR = (R & 7) ^ ((R >> 3) & 7);
        o0[i] = (short)tile[R][(((sc >> 3) ^ sR) * 8) + (sc & 7)];
    }
    #pragma unroll
    for (int i = 0; i < 8; ++i) {
        const int R = rg2 + 8 + i;
        const int sR = (R & 7) ^ ((R >> 3) & 7);
        o1[i] = (short)tile[R][(((sc >> 3) ^ sR) * 8) + (sc & 7)];
    }
    u16* dT = dstT + ((size_t)b * N_ + c0 + sc) * N_ + r0 + rg2;
    *(bf16x8*)dT = o0;
    *(bf16x8*)(dT + 8) = o1;
}

// ---------------------------------------------------------------------------
// K2: per-layer refine gate + x transposed to bf16 [B, D, N] (+ FC weight cvt)
__global__ __launch_bounds__(256) void k_gate_xt(
    const float* __restrict__ x, const float* __restrict__ rg,
    float* __restrict__ gate, u16* __restrict__ xT,
    const float* __restrict__ wi, const float* __restrict__ wo,
    u16* __restrict__ wib, u16* __restrict__ wob)
{
    if (blockIdx.y >= B_) {
        const int i = ((blockIdx.y - B_) * 32 + blockIdx.x) * 256 + threadIdx.x;
        wib[i] = f2bf(wi[i]);
        wob[i] = f2bf(wo[i]);
        return;
    }

    __shared__ u16 lx[D_][36];
    __shared__ float srg[D_];
    const int b = blockIdx.y, n0 = blockIdx.x * 32;
    const int t = threadIdx.x;
    srg[t] = rg[t];
    __syncthreads();

    const int r = t >> 3, cg = t & 7;
    const float* xrow = x + ((size_t)b * N_ + n0 + r) * D_;
    float dot = 0.f;
    #pragma unroll
    for (int u = 0; u < 8; ++u) {
        const int c = cg * 32 + u * 4;
        const float4 v = *(const float4*)(xrow + c);
        lx[c][r] = f2bf(v.x); lx[c + 1][r] = f2bf(v.y);
        lx[c + 2][r] = f2bf(v.z); lx[c + 3][r] = f2bf(v.w);
        dot += v.x * srg[c] + v.y * srg[c + 1] + v.z * srg[c + 2] + v.w * srg[c + 3];
    }
    dot += __shfl_down(dot, 4, 8);
    dot += __shfl_down(dot, 2, 8);
    dot += __shfl_down(dot, 1, 8);
    if (cg == 0) gate[(size_t)b * N_ + n0 + r] = 1.f / (1.f + expf(-dot));
    __syncthreads();

    #pragma unroll
    for (int i = 0; i < 8; ++i) {
        const int unit = i * 256 + t;
        const int d = unit >> 3, nch = (unit & 7) * 4;
        ushort4 wv;
        wv.x = lx[d][nch];     wv.y = lx[d][nch + 1];
        wv.z = lx[d][nch + 2]; wv.w = lx[d][nch + 3];
        *(ushort4*)(xT + ((size_t)b * D_ + d) * N_ + n0 + nch) = wv;
    }
}

// ---------------------------------------------------------------------------
// K3 v6: single blended GEMM, round-8 FIFO discipline (2-deep A rotation),
// re-tiled 64m x 256n, 4 waves, grid 512 = exactly 2 blocks/CU so independent
// blocks overlap each other's barrier stalls (cross-block waves share no
// barrier). Steady entry FIFO [A(ks+2)x2, B(ks+1)x4]: blend's implicit wait
// retires A(ks+2); explicit vmcnt(6) retires B(ks+1), keeps A(ks+3)+B(ks+2).
__global__ __launch_bounds__(256, 2) void k_gemm_ax(
    const u16* __restrict__ depb, const u16* __restrict__ latb,
    const u16* __restrict__ depTb, const u16* __restrict__ latTb,
    const u16* __restrict__ xT,
    const float* __restrict__ gate,
    const float* __restrict__ Wgi, const float* __restrict__ Wgo,
    const float* __restrict__ bgi, const float* __restrict__ bgo,
    const float* __restrict__ xcur,
    u16* __restrict__ axin, u16* __restrict__ axout)
{
    // 2 bufs x 20480B (A[64][32] 4KB + B[256][32] 16KB); hbuf aliases low 33.3KB
    __shared__ __align__(16) char smem[42240];
    u16* const sb = (u16*)smem;
    float* hbuf = (float*)smem;                 // [32][260] per store pass
    float* psum = (float*)(smem + 40960);       // [64][4]
    float* sh_s = (float*)(smem + 41984);       // [64]

    // bijective XCD swizzle: 512 blocks, 64/XCD; each XCD owns 2 full batches
    const int bid = blockIdx.x;
    const int logical = (bid & 7) * 64 + (bid >> 3);
    const int b = logical >> 5;
    const int rem = logical & 31;
    const int z = rem >> 4;
    const int m0 = (rem & 15) * 64;

    const u16* A1 = z ? depTb : depb;
    const u16* A2 = z ? latTb : latb;
    const float* Wg = z ? Wgo : Wgi;
    const float bg0 = z ? bgo[0] : bgi[0];
    u16* outp = z ? axout : axin;

    const int t = threadIdx.x;                  // 0..255
    const int lane = t & 63;
    const int w = t >> 6;                        // 0..3 (n-quarter)

    // A staging: thread t -> row t>>2 (0..63), k-granule t&3 (8 bf16)
    const int arow = t >> 2;
    const int akq = t & 3;
    const float gv = gate[(size_t)b * N_ + m0 + arow];
    const u16* gA1 = A1 + ((size_t)b * N_ + m0 + arow) * N_ + akq * 8;
    const u16* gA2 = A2 + ((size_t)b * N_ + m0 + arow) * N_ + akq * 8;
    const int awoff = arow * 32 + ((akq ^ ((arow >> 1) & 3)) << 3);

    // B dma: wave w stages 16-row chunks 4w..4w+3 (pre-swizzled source)
    const int rl = lane >> 2;
    const int kk = (((lane & 3) ^ ((lane >> 3) & 3)) << 3);
    const u16* gB[4];
    int boff[4];
    #pragma unroll
    for (int j = 0; j < 4; ++j) {
        const int ch = w * 4 + j;
        gB[j] = xT + ((size_t)b * D_ + ch * 16 + rl) * N_ + kk;
        boff[j] = 2048 + ch * 512;
    }

    const int mrow = lane & 15;
    const int hi = lane >> 4;
    const int kg = (((lane >> 4) ^ ((mrow >> 1) & 3)) << 3);

    f32x4 acc[4][4];
    const f32x4 fz = {0.f, 0.f, 0.f, 0.f};
    #pragma unroll
    for (int i = 0; i < 4; ++i)
        #pragma unroll
        for (int j = 0; j < 4; ++j) acc[i][j] = fz;

    bf16x8 rA1x, rA2x, rA1y, rA2y;

    auto blend_store = [&](const bf16x8& a1v, const bf16x8& a2v, u16* dst) {
        bf16x8 bl;
        #pragma unroll
        for (int u = 0; u < 8; ++u) {
            const float f1 = bf2f((u16)a1v[u]);
            const float f2 = bf2f((u16)a2v[u]);
            bl[u] = (short)f2bf(f2 + gv * (f1 - f2));
        }
        *(bf16x8*)dst = bl;
    };

    // prologue: invariant at body(0) entry = FIFO [A(2)x2, B(1)x4]
    rA1x = *(const bf16x8*)(gA1);       rA2x = *(const bf16x8*)(gA2);
    blend_store(rA1x, rA2x, sb + awoff);                       // A(0) -> buf0
    rA1x = *(const bf16x8*)(gA1 + 32);  rA2x = *(const bf16x8*)(gA2 + 32);
    blend_store(rA1x, rA2x, sb + 10240 + awoff);               // A(1) -> buf1
    #pragma unroll
    for (int j = 0; j < 4; ++j) gl_lds16(gB[j], sb + boff[j]);           // B(0)
    rA1x = *(const bf16x8*)(gA1 + 64);  rA2x = *(const bf16x8*)(gA2 + 64);  // A(2)
    #pragma unroll
    for (int j = 0; j < 4; ++j) gl_lds16(gB[j] + 32, sb + 10240 + boff[j]); // B(1)
    vm_wait6();   // FIFO [B0x4, A2x2, B1x4] -> retire B(0)
    lgkm0();
    schedb(); __builtin_amdgcn_s_barrier(); schedb();

    auto body = [&](int ks, bf16x8& c1, bf16x8& c2, bf16x8& n1, bf16x8& n2) {
        if (ks <= 28) {                                        // issue A(ks+3) regs
            n1 = *(const bf16x8*)(gA1 + (ks + 3) * 32);
            n2 = *(const bf16x8*)(gA2 + (ks + 3) * 32);
        }
        schedb();
        const u16* sA = sb + (ks & 1) * 10240;
        const u16* sBc = sA + 2048;
        bf16x8 a[4], fbv[4];
        #pragma unroll
        for (int mt = 0; mt < 4; ++mt)
            a[mt] = *(const bf16x8*)(sA + (mt * 16 + mrow) * 32 + kg);
        #pragma unroll
        for (int nt = 0; nt < 4; ++nt)
            fbv[nt] = *(const bf16x8*)(sBc + (w * 64 + nt * 16 + mrow) * 32 + kg);
        #pragma unroll
        for (int mt = 0; mt < 4; ++mt)
            #pragma unroll
            for (int nt = 0; nt < 4; ++nt)
                acc[mt][nt] = __builtin_amdgcn_mfma_f32_16x16x32_bf16(a[mt], fbv[nt], acc[mt][nt], 0, 0, 0);
        schedb();
        __builtin_amdgcn_s_barrier();       // all waves done reading cur
        schedb();
        if (ks <= 29) {                      // tile ks+2 -> cur buffer
            u16* cb = sb + (ks & 1) * 10240;
            blend_store(c1, c2, cb + awoff); // implicit wait retires A(ks+2)
            #pragma unroll
            for (int j = 0; j < 4; ++j) gl_lds16(gB[j] + (ks + 2) * 32, cb + boff[j]);
        }
        if (ks <= 28) vm_wait6();            // retire B(ks+1); keep A(ks+3)+B(ks+2)
        else if (ks == 29) vm_wait4();       // retire B(30); keep B(31)
        else if (ks == 30) vm_wait0();       // retire B(31)
        lgkm0();
        schedb();
        __builtin_amdgcn_s_barrier();
        schedb();
    };

    for (int kp = 0; kp < 16; ++kp) {
        body(2 * kp,     rA1x, rA2x, rA1y, rA2y);
        body(2 * kp + 1, rA1y, rA2y, rA1x, rA2x);
    }
    __syncthreads();

    // gcn-gate: full-row dot from acc regs
    float wgv[4];
    #pragma unroll
    for (int nt = 0; nt < 4; ++nt) wgv[nt] = Wg[w * 64 + nt * 16 + mrow];
    #pragma unroll
    for (int mt = 0; mt < 4; ++mt) {
        #pragma unroll
        for (int rr = 0; rr < 4; ++rr) {
            float p = acc[mt][0][rr] * wgv[0] + acc[mt][1][rr] * wgv[1]
                    + acc[mt][2][rr] * wgv[2] + acc[mt][3][rr] * wgv[3];
            p += __shfl_xor(p, 1, 16);
            p += __shfl_xor(p, 2, 16);
            p += __shfl_xor(p, 4, 16);
            p += __shfl_xor(p, 8, 16);
            if (mrow == 0) psum[(mt * 16 + hi * 4 + rr) * 4 + w] = p;
        }
    }
    __syncthreads();
    if (t < 64) {
        const float d = psum[t * 4] + psum[t * 4 + 1] + psum[t * 4 + 2] + psum[t * 4 + 3];
        sh_s[t] = 1.f / (1.f + expf(-d));
    }
    __syncthreads();

    // 2 store passes of 32 rows each (every wave holds all 64 rows)
    #pragma unroll
    for (int p = 0; p < 2; ++p) {
        #pragma unroll
        for (int mtl = 0; mtl < 2; ++mtl) {
            const int mt = p * 2 + mtl;
            #pragma unroll
            for (int nt = 0; nt < 4; ++nt) {
                const int col = w * 64 + nt * 16 + mrow;
                #pragma unroll
                for (int rr = 0; rr < 4; ++rr) {
                    const int hrow = mtl * 16 + hi * 4 + rr;
                    hbuf[hrow * 260 + col] = acc[mt][nt][rr];
                }
            }
        }
        __syncthreads();
        {
            const int sr = t >> 3;                 // 0..31
            const int c0 = (t & 7) * 32;
            const float s = sh_s[p * 32 + sr];
            const size_t gb = ((size_t)b * N_ + m0 + p * 32 + sr) * D_ + c0;
            const float* xr = xcur + gb;
            u16* orow = outp + gb;
            bf16x8 o0, o1, o2, o3;
            #pragma unroll
            for (int u = 0; u < 8; ++u)
                o0[u] = (short)f2bf(hbuf[sr * 260 + c0 + u] * s + bg0 + xr[u]);
            #pragma unroll
            for (int u = 0; u < 8; ++u)
                o1[u] = (short)f2bf(hbuf[sr * 260 + c0 + 8 + u] * s + bg0 + xr[8 + u]);
            #pragma unroll
            for (int u = 0; u < 8; ++u)
                o2[u] = (short)f2bf(hbuf[sr * 260 + c0 + 16 + u] * s + bg0 + xr[16 + u]);
            #pragma unroll
            for (int u = 0; u < 8; ++u)
                o3[u] = (short)f2bf(hbuf[sr * 260 + c0 + 24 + u] * s + bg0 + xr[24 + u]);
            *(bf16x8*)orow = o0;
            *(bf16x8*)(orow + 8) = o1;
            *(bf16x8*)(orow + 16) = o2;
            *(bf16x8*)(orow + 24) = o3;
        }
        __syncthreads();
    }
}

// ---------------------------------------------------------------------------
// K4: gemm-skeleton fc_ln. Tile 64m x 256n, 8 waves; LN stats from acc regs.
// Grid 256 = 1 block/CU. (unchanged from round 8)
__global__ __launch_bounds__(512, 2) void k_fc_ln(
    const u16* __restrict__ axin, const u16* __restrict__ axout,
    const u16* __restrict__ Wib, const u16* __restrict__ Wob,
    const float* __restrict__ bi, const float* __restrict__ bo,
    const float* __restrict__ lg, const float* __restrict__ lb,
    float* __restrict__ outp)
{
    __shared__ __align__(16) char smem[51712];
    u16* const sb = (u16*)smem;
    float* hbuf = (float*)smem;
    float* psum = (float*)(smem + 49152);
    float* sh_mu = (float*)(smem + 51200);
    float* sh_rs = (float*)(smem + 51456);

    const int bid = blockIdx.x;
    const int logical = (bid & 7) * 32 + (bid >> 3);
    const int b = logical >> 4;
    const int m0 = (logical & 15) * 64;

    const int t = threadIdx.x, lane = t & 63, w = t >> 6;
    const int wr = w >> 2, wc = w & 3;
    const int half = wc >> 1;

    const int rl = lane >> 2;
    const int kk = (((lane & 3) ^ ((lane >> 3) & 3)) << 3);

    const u16* gsrc[3];
    int loff[3];
    #pragma unroll
    for (int ci = 0; ci < 3; ++ci) {
        const int c = w * 3 + ci;
        if (c < 4) {
            gsrc[ci] = axin + ((size_t)b * N_ + m0 + c * 16 + rl) * D_ + kk;
            loff[ci] = c * 512;
        } else if (c < 8) {
            gsrc[ci] = axout + ((size_t)b * N_ + m0 + (c - 4) * 16 + rl) * D_ + kk;
            loff[ci] = 2048 + (c - 4) * 512;
        } else {
            const int cw = c - 8;
            const u16* base = (cw < 8) ? (Wib + (size_t)(cw * 16 + rl) * D_)
                                       : (Wob + (size_t)((cw - 8) * 16 + rl) * D_);
            gsrc[ci] = base + kk;
            loff[ci] = 4096 + cw * 512;
        }
    }

    f32x4 acc[2][4];
    const f32x4 fz = {0.f, 0.f, 0.f, 0.f};
    #pragma unroll
    for (int i = 0; i < 2; ++i)
        #pragma unroll
        for (int j = 0; j < 4; ++j) acc[i][j] = fz;

    #pragma unroll
    for (int ci = 0; ci < 3; ++ci) gl_lds16(gsrc[ci], sb + loff[ci]);
    #pragma unroll
    for (int ci = 0; ci < 3; ++ci) gl_lds16(gsrc[ci] + 32, sb + 12288 + loff[ci]);
    vm_wait3();
    lgkm0();
    schedb(); __builtin_amdgcn_s_barrier(); schedb();

    const int mrow = lane & 15;
    const int hi = lane >> 4;
    const int kg = (((lane >> 4) ^ ((mrow >> 1) & 3)) << 3);

    for (int ks = 0; ks < 8; ++ks) {
        const u16* cur = sb + (ks & 1) * 12288;
        const u16* sA = cur + (half ? 2048 : 0);
        const u16* sW = cur + 4096;
        bf16x8 a[2], fbv[4];
        #pragma unroll
        for (int mt = 0; mt < 2; ++mt)
            a[mt] = *(const bf16x8*)(sA + (wr * 32 + mt * 16 + mrow) * 32 + kg);
        #pragma unroll
        for (int nt = 0; nt < 4; ++nt)
            fbv[nt] = *(const bf16x8*)(sW + (wc * 64 + nt * 16 + mrow) * 32 + kg);
        #pragma unroll
        for (int mt = 0; mt < 2; ++mt)
            #pragma unroll
            for (int nt = 0; nt < 4; ++nt)
                acc[mt][nt] = __builtin_amdgcn_mfma_f32_16x16x32_bf16(a[mt], fbv[nt], acc[mt][nt], 0, 0, 0);
        schedb();
        __builtin_amdgcn_s_barrier();
        schedb();
        if (ks <= 5) {
            u16* nb = sb + (ks & 1) * 12288;
            #pragma unroll
            for (int ci = 0; ci < 3; ++ci) gl_lds16(gsrc[ci] + (ks + 2) * 32, nb + loff[ci]);
        }
        if (ks <= 5) vm_wait3();
        else if (ks == 6) vm_wait0();
        lgkm0();
        schedb();
        __builtin_amdgcn_s_barrier();
        schedb();
    }
    __syncthreads();

    float bc[4];
    #pragma unroll
    for (int nt = 0; nt < 4; ++nt) {
        const int colh = wc * 64 + nt * 16 + mrow;
        bc[nt] = 2.f * (colh < 128 ? bi[colh] : bo[colh - 128]);
    }
    #pragma unroll
    for (int mt = 0; mt < 2; ++mt)
        #pragma unroll
        for (int rr = 0; rr < 4; ++rr) {
            const int lrow = wr * 32 + mt * 16 + hi * 4 + rr;
            float s = 0.f, ss = 0.f;
            #pragma unroll
            for (int nt = 0; nt < 4; ++nt) {
                const float v = acc[mt][nt][rr] + bc[nt];
                s += v; ss += v * v;
            }
            s += __shfl_xor(s, 1, 16);  ss += __shfl_xor(ss, 1, 16);
            s += __shfl_xor(s, 2, 16);  ss += __shfl_xor(ss, 2, 16);
            s += __shfl_xor(s, 4, 16);  ss += __shfl_xor(ss, 4, 16);
            s += __shfl_xor(s, 8, 16);  ss += __shfl_xor(ss, 8, 16);
            if (mrow == 0) {
                psum[lrow * 8 + wc * 2] = s;
                psum[lrow * 8 + wc * 2 + 1] = ss;
            }
        }
    __syncthreads();
    if (t < 64) {
        const float s = psum[t * 8] + psum[t * 8 + 2] + psum[t * 8 + 4] + psum[t * 8 + 6];
        const float ss = psum[t * 8 + 1] + psum[t * 8 + 3] + psum[t * 8 + 5] + psum[t * 8 + 7];
        const float mu = s * (1.f / 256.f);
        const float var = ss * (1.f / 256.f) - mu * mu;
        sh_mu[t] = mu;
        sh_rs[t] = rsqrtf(var + 1e-5f);
    }
    __syncthreads();

    #pragma unroll
    for (int p = 0; p < 2; ++p) {
        if (wr == p) {
            #pragma unroll
            for (int mt = 0; mt < 2; ++mt)
                #pragma unroll
                for (int nt = 0; nt < 4; ++nt) {
                    const int col = wc * 64 + nt * 16 + mrow;
                    #pragma unroll
                    for (int rr = 0; rr < 4; ++rr) {
                        const int hrow = mt * 16 + hi * 4 + rr;
                        hbuf[hrow * 260 + col] = acc[mt][nt][rr] + bc[nt];
                    }
                }
        }
        __syncthreads();
        {
            const int sr = t >> 4;
            const int sc0 = (t & 15) * 16;
            const int grow = p * 32 + sr;
            const float mu = sh_mu[grow], rs = sh_rs[grow];
            float* orow = outp + ((size_t)b * N_ + m0 + grow) * D_ + sc0;
            #pragma unroll
            for (int q = 0; q < 4; ++q) {
                const float4 gg = *(const float4*)(lg + sc0 + q * 4);
                const float4 bb = *(const float4*)(lb + sc0 + q * 4);
                float4 o;
                const float v0 = (hbuf[sr * 260 + sc0 + q * 4    ] - mu) * rs * gg.x + bb.x;
                const float v1 = (hbuf[sr * 260 + sc0 + q * 4 + 1] - mu) * rs * gg.y + bb.y;
                const float v2 = (hbuf[sr * 260 + sc0 + q * 4 + 2] - mu) * rs * gg.z + bb.z;
                const float v3 = (hbuf[sr * 260 + sc0 + q * 4 + 3] - mu) * rs * gg.w + bb.w;
                o.x = 0.5f * v0 * (1.f + erff(v0 * 0.70710678118654752f));
                o.y = 0.5f * v1 * (1.f + erff(v1 * 0.70710678118654752f));
                o.z = 0.5f * v2 * (1.f + erff(v2 * 0.70710678118654752f));
                o.w = 0.5f * v3 * (1.f + erff(v3 * 0.70710678118654752f));
                *(float4*)(orow + q * 4) = o;
            }
        }
        __syncthreads();
    }
}

// ---------------------------------------------------------------------------
extern "C" void kernel_launch(void* const* d_in, const int* in_sizes, int n_in,
                              void* d_out, int out_size, void* d_ws, size_t ws_size,
                              hipStream_t stream)
{
    (void)in_sizes; (void)n_in; (void)out_size; (void)ws_size;

    const float* x0  = (const float*)d_in[0];
    const float* lat = (const float*)d_in[1];
    const float* dep = (const float*)d_in[2];
    const float* rg  = (const float*)d_in[3];
    const float* Wgi = (const float*)d_in[4];
    const float* bgi = (const float*)d_in[5];
    const float* Wgo = (const float*)d_in[6];
    const float* bgo = (const float*)d_in[7];
    const float* fiW = (const float*)d_in[8];
    const float* fib = (const float*)d_in[9];
    const float* foW = (const float*)d_in[10];
    const float* fob = (const float*)d_in[11];
    const float* lng = (const float*)d_in[12];
    const float* lnb = (const float*)d_in[13];

    char* ws = (char*)d_ws;
    size_t off = 0;
    auto alloc = [&](size_t bytes) {
        char* p = ws + off;
        off += (bytes + 255) & ~(size_t)255;
        return p;
    };
    u16* depb  = (u16*)alloc(2ull * B_ * N_ * N_);
    u16* latb  = (u16*)alloc(2ull * B_ * N_ * N_);
    u16* depTb = (u16*)alloc(2ull * B_ * N_ * N_);
    u16* latTb = (u16*)alloc(2ull * B_ * N_ * N_);
    u16* xT    = (u16*)alloc(2ull * B_ * D_ * N_);
    u16* axin  = (u16*)alloc(2ull * B_ * N_ * D_);
    u16* axout = (u16*)alloc(2ull * B_ * N_ * D_);
    float* gate = (float*)alloc(4ull * B_ * N_);
    float* xbuf = (float*)alloc(4ull * B_ * N_ * D_);
    u16* Wib = (u16*)alloc(2ull * H_ * D_);
    u16* Wob = (u16*)alloc(2ull * H_ * D_);

    k_conv_adj<<<dim3(16, 16, 32), 256, 0, stream>>>(dep, lat, depb, latb, depTb, latTb);

    const float* xcur = x0;
    for (int l = 0; l < 2; ++l) {
        k_gate_xt<<<dim3(32, B_ + 4), 256, 0, stream>>>(
            xcur, rg + l * D_, gate, xT,
            fiW + (size_t)l * H_ * D_, foW + (size_t)l * H_ * D_, Wib, Wob);
        k_gemm_ax<<<dim3(512), 256, 0, stream>>>(
            depb, latb, depTb, latTb, xT, gate,
            Wgi + l * D_, Wgo + l * D_, bgi + l, bgo + l,
            xcur, axin, axout);
        const bool last = (l == 1);
        k_fc_ln<<<dim3(256), 512, 0, stream>>>(
            axin, axout, Wib, Wob,
            fib + l * H_, fob + l * H_,
            lng + l * 2 * H_, lnb + l * 2 * H_,
            last ? (float*)d_out : xbuf);
        xcur = xbuf;
    }
}

// Round 11
// 320.794 us; speedup vs baseline: 1.0744x; 1.0744x over previous
//
#include <hip/hip_runtime.h>
#include <hip/hip_bf16.h>
#include <cstdint>

#define B_ 16
#define N_ 1024
#define D_ 256
#define H_ 128

typedef unsigned short u16;
typedef __attribute__((ext_vector_type(8))) short bf16x8;
typedef __attribute__((ext_vector_type(4))) float f32x4;

__device__ __forceinline__ u16 f2bf(float f) {
    union { float f; uint32_t u; } v; v.f = f;
    return (u16)((v.u + 0x7FFFu + ((v.u >> 16) & 1u)) >> 16);  // RNE
}
__device__ __forceinline__ float bf2f(u16 h) {
    union { uint32_t u; float f; } v; v.u = ((uint32_t)h) << 16;
    return v.f;
}

typedef __attribute__((address_space(3))) void lds_void;
typedef const __attribute__((address_space(1))) void g_void;

__device__ __forceinline__ void gl_lds16(const void* g, void* l) {
    __builtin_amdgcn_global_load_lds((g_void*)g, (lds_void*)l, 16, 0, 0);
}

__device__ __forceinline__ void vm_wait4() { asm volatile("s_waitcnt vmcnt(4)" ::: "memory"); }
__device__ __forceinline__ void vm_wait3() { asm volatile("s_waitcnt vmcnt(3)" ::: "memory"); }
__device__ __forceinline__ void vm_wait2() { asm volatile("s_waitcnt vmcnt(2)" ::: "memory"); }
__device__ __forceinline__ void vm_wait0() { asm volatile("s_waitcnt vmcnt(0)" ::: "memory"); }
__device__ __forceinline__ void lgkm0()   { asm volatile("s_waitcnt lgkmcnt(0)" ::: "memory"); }
__device__ __forceinline__ void schedb()  { __builtin_amdgcn_sched_barrier(0); }

// ---------------------------------------------------------------------------
// K1: fp32 adjacencies -> bf16 (normal + transposed). 64x64 tiles, conflict-
// free swizzle (slot = g ^ ((r&7)^((r>>3)&7)); measured 0 conflicts r8).
// grid (16, 16, B*2), block 256.
__global__ __launch_bounds__(256) void k_conv_adj(
    const float* __restrict__ dep, const float* __restrict__ lat,
    u16* __restrict__ depb, u16* __restrict__ latb,
    u16* __restrict__ depTb, u16* __restrict__ latTb)
{
    __shared__ u16 tile[64][64];
    const int bz = blockIdx.z;
    const int b = bz >> 1;
    const float* src = (bz & 1) ? lat : dep;
    u16* dstN = (bz & 1) ? latb : depb;
    u16* dstT = (bz & 1) ? latTb : depTb;
    const int r0 = blockIdx.y * 64, c0 = blockIdx.x * 64;
    const int t = threadIdx.x;
    const int r = t >> 2, cg = (t & 3) * 16;

    const float* srow = src + ((size_t)b * N_ + r0 + r) * N_ + c0 + cg;
    bf16x8 lo, hi;
    {
        const float4 v0 = *(const float4*)(srow);
        const float4 v1 = *(const float4*)(srow + 4);
        const float4 v2 = *(const float4*)(srow + 8);
        const float4 v3 = *(const float4*)(srow + 12);
        lo[0] = (short)f2bf(v0.x); lo[1] = (short)f2bf(v0.y); lo[2] = (short)f2bf(v0.z); lo[3] = (short)f2bf(v0.w);
        lo[4] = (short)f2bf(v1.x); lo[5] = (short)f2bf(v1.y); lo[6] = (short)f2bf(v1.z); lo[7] = (short)f2bf(v1.w);
        hi[0] = (short)f2bf(v2.x); hi[1] = (short)f2bf(v2.y); hi[2] = (short)f2bf(v2.z); hi[3] = (short)f2bf(v2.w);
        hi[4] = (short)f2bf(v3.x); hi[5] = (short)f2bf(v3.y); hi[6] = (short)f2bf(v3.z); hi[7] = (short)f2bf(v3.w);
    }
    u16* nrow = dstN + ((size_t)b * N_ + r0 + r) * N_ + c0 + cg;
    *(bf16x8*)nrow = lo;
    *(bf16x8*)(nrow + 8) = hi;

    const int g0 = (t & 3) * 2;
    const int s = (r & 7) ^ ((r >> 3) & 7);
    *(bf16x8*)(&tile[r][((g0    ) ^ s) * 8]) = lo;
    *(bf16x8*)(&tile[r][((g0 + 1) ^ s) * 8]) = hi;
    __syncthreads();

    const int sc = t >> 2, rg2 = (t & 3) * 16;
    bf16x8 o0, o1;
    #pragma unroll
    for (int i = 0; i < 8; ++i) {
        const int R = rg2 + i;
        const int sR = (R & 7) ^ ((R >> 3) & 7);
        o0[i] = (short)tile[R][(((sc >> 3) ^ sR) * 8) + (sc & 7)];
    }
    #pragma unroll
    for (int i = 0; i < 8; ++i) {
        const int R = rg2 + 8 + i;
        const int sR = (R & 7) ^ ((R >> 3) & 7);
        o1[i] = (short)tile[R][(((sc >> 3) ^ sR) * 8) + (sc & 7)];
    }
    u16* dT = dstT + ((size_t)b * N_ + c0 + sc) * N_ + r0 + rg2;
    *(bf16x8*)dT = o0;
    *(bf16x8*)(dT + 8) = o1;
}

// ---------------------------------------------------------------------------
// K2: layer-0 refine gate + x0 transposed to bf16 [B, D, N]. Extra y-slices
// (y >= B, 8 of them) convert BOTH layers' FC weights (2 x H x D each).
__global__ __launch_bounds__(256) void k_gate_xt(
    const float* __restrict__ x, const float* __restrict__ rg,
    float* __restrict__ gate, u16* __restrict__ xT,
    const float* __restrict__ wi, const float* __restrict__ wo,
    u16* __restrict__ wib, u16* __restrict__ wob)
{
    if (blockIdx.y >= B_) {
        const int i = ((blockIdx.y - B_) * 32 + blockIdx.x) * 256 + threadIdx.x;  // [0, 65536)
        wib[i] = f2bf(wi[i]);
        wob[i] = f2bf(wo[i]);
        return;
    }

    __shared__ u16 lx[D_][36];
    __shared__ float srg[D_];
    const int b = blockIdx.y, n0 = blockIdx.x * 32;
    const int t = threadIdx.x;
    srg[t] = rg[t];
    __syncthreads();

    const int r = t >> 3, cg = t & 7;
    const float* xrow = x + ((size_t)b * N_ + n0 + r) * D_;
    float dot = 0.f;
    #pragma unroll
    for (int u = 0; u < 8; ++u) {
        const int c = cg * 32 + u * 4;
        const float4 v = *(const float4*)(xrow + c);
        lx[c][r] = f2bf(v.x); lx[c + 1][r] = f2bf(v.y);
        lx[c + 2][r] = f2bf(v.z); lx[c + 3][r] = f2bf(v.w);
        dot += v.x * srg[c] + v.y * srg[c + 1] + v.z * srg[c + 2] + v.w * srg[c + 3];
    }
    dot += __shfl_down(dot, 4, 8);
    dot += __shfl_down(dot, 2, 8);
    dot += __shfl_down(dot, 1, 8);
    if (cg == 0) gate[(size_t)b * N_ + n0 + r] = 1.f / (1.f + expf(-dot));
    __syncthreads();

    #pragma unroll
    for (int i = 0; i < 8; ++i) {
        const int unit = i * 256 + t;
        const int d = unit >> 3, nch = (unit & 7) * 4;
        ushort4 wv;
        wv.x = lx[d][nch];     wv.y = lx[d][nch + 1];
        wv.z = lx[d][nch + 2]; wv.w = lx[d][nch + 3];
        *(ushort4*)(xT + ((size_t)b * D_ + d) * N_ + n0 + nch) = wv;
    }
}

// ---------------------------------------------------------------------------
// K3: single blended GEMM (round-8 measured-best config, restored verbatim).
// Tile 128m x 256n, BK=32, 8 waves, grid 256 = 1 block/CU, XCD swizzle.
// A reg-staged (issue ks+3, blend+ds_write ks+2); B via global_load_lds
// (issue ks+2); counted vmcnt(4) steady, never drained in-loop.
__global__ __launch_bounds__(512, 2) void k_gemm_ax(
    const u16* __restrict__ depb, const u16* __restrict__ latb,
    const u16* __restrict__ depTb, const u16* __restrict__ latTb,
    const u16* __restrict__ xT,
    const float* __restrict__ gate,
    const float* __restrict__ Wgi, const float* __restrict__ Wgo,
    const float* __restrict__ bgi, const float* __restrict__ bgo,
    const float* __restrict__ xcur,
    u16* __restrict__ axin, u16* __restrict__ axout)
{
    __shared__ __align__(16) char smem[51712];
    u16* const sb = (u16*)smem;                 // 2 bufs x 12288 u16 [A 4096|B 8192]
    float* hbuf = (float*)smem;                 // epilogue alias [32][260]
    float* psum = (float*)(smem + 49152);       // [128][4]
    float* sh_s = (float*)(smem + 51200);       // [128]

    const int bid = blockIdx.x;
    const int logical = (bid & 7) * 32 + (bid >> 3);
    const int b = logical >> 4;
    const int rem = logical & 15;
    const int z = rem >> 3;
    const int m0 = (rem & 7) * 128;

    const u16* A1 = z ? depTb : depb;
    const u16* A2 = z ? latTb : latb;
    const float* Wg = z ? Wgo : Wgi;
    const float bg0 = z ? bgo[0] : bgi[0];
    u16* outp = z ? axout : axin;

    const int t = threadIdx.x;
    const int lane = t & 63;
    const int w = t >> 6;
    const int wr = w >> 2, wc = w & 3;

    const int arow = t >> 2;
    const int akq = t & 3;
    const float gv = gate[(size_t)b * N_ + m0 + arow];
    const u16* gA1 = A1 + ((size_t)b * N_ + m0 + arow) * N_ + akq * 8;
    const u16* gA2 = A2 + ((size_t)b * N_ + m0 + arow) * N_ + akq * 8;
    const int awoff = arow * 32 + ((akq ^ ((arow >> 1) & 3)) << 3);

    const int rl = lane >> 2;
    const int kk = (((lane & 3) ^ ((lane >> 3) & 3)) << 3);
    const u16* gB0 = xT + ((size_t)b * D_ + (w * 2) * 16 + rl) * N_ + kk;
    const u16* gB1 = xT + ((size_t)b * D_ + (w * 2 + 1) * 16 + rl) * N_ + kk;
    const int boff0 = 4096 + (w * 2) * 512;
    const int boff1 = 4096 + (w * 2 + 1) * 512;

    const int mrow = lane & 15;
    const int hi = lane >> 4;
    const int kg = (((lane >> 4) ^ ((mrow >> 1) & 3)) << 3);

    f32x4 acc[4][4];
    const f32x4 fz = {0.f, 0.f, 0.f, 0.f};
    #pragma unroll
    for (int i = 0; i < 4; ++i)
        #pragma unroll
        for (int j = 0; j < 4; ++j) acc[i][j] = fz;

    bf16x8 rA1x, rA2x, rA1y, rA2y;

    auto blend_store = [&](const bf16x8& a1v, const bf16x8& a2v, u16* dst) {
        bf16x8 bl;
        #pragma unroll
        for (int u = 0; u < 8; ++u) {
            const float f1 = bf2f((u16)a1v[u]);
            const float f2 = bf2f((u16)a2v[u]);
            bl[u] = (short)f2bf(f2 + gv * (f1 - f2));
        }
        *(bf16x8*)dst = bl;
    };

    // prologue: tiles 0,1 staged; A(2) regs in flight
    rA1x = *(const bf16x8*)(gA1);       rA2x = *(const bf16x8*)(gA2);
    blend_store(rA1x, rA2x, sb + awoff);                       // A(0) -> buf0
    rA1x = *(const bf16x8*)(gA1 + 32);  rA2x = *(const bf16x8*)(gA2 + 32);
    gl_lds16(gB0, sb + boff0);          gl_lds16(gB1, sb + boff1);          // B(0)
    blend_store(rA1x, rA2x, sb + 12288 + awoff);               // A(1) -> buf1
    rA1x = *(const bf16x8*)(gA1 + 64);  rA2x = *(const bf16x8*)(gA2 + 64);  // A(2)
    gl_lds16(gB0 + 32, sb + 12288 + boff0); gl_lds16(gB1 + 32, sb + 12288 + boff1);
    vm_wait2();   // FIFO [A2x2,B0x2,B1x2]: retires A2+B0, keeps B1
    lgkm0();
    schedb(); __builtin_amdgcn_s_barrier(); schedb();

    auto body = [&](int ks, bf16x8& c1, bf16x8& c2, bf16x8& n1, bf16x8& n2) {
        if (ks <= 28) {                                        // issue A(ks+3) regs
            n1 = *(const bf16x8*)(gA1 + (ks + 3) * 32);
            n2 = *(const bf16x8*)(gA2 + (ks + 3) * 32);
        }
        const u16* sA = sb + (ks & 1) * 12288;
        const u16* sBc = sA + 4096;
        bf16x8 a[4], fbv[4];
        #pragma unroll
        for (int mt = 0; mt < 4; ++mt)
            a[mt] = *(const bf16x8*)(sA + (wr * 64 + mt * 16 + mrow) * 32 + kg);
        #pragma unroll
        for (int nt = 0; nt < 4; ++nt)
            fbv[nt] = *(const bf16x8*)(sBc + (wc * 64 + nt * 16 + mrow) * 32 + kg);
        #pragma unroll
        for (int mt = 0; mt < 4; ++mt)
            #pragma unroll
            for (int nt = 0; nt < 4; ++nt)
                acc[mt][nt] = __builtin_amdgcn_mfma_f32_16x16x32_bf16(a[mt], fbv[nt], acc[mt][nt], 0, 0, 0);
        schedb();
        __builtin_amdgcn_s_barrier();       // all waves done reading cur
        schedb();
        if (ks <= 29) {                      // tile ks+2 -> cur buffer
            u16* cb = sb + (ks & 1) * 12288;
            blend_store(c1, c2, cb + awoff); // implicit wait retires A(ks+2)
            gl_lds16(gB0 + (ks + 2) * 32, cb + boff0);
            gl_lds16(gB1 + (ks + 2) * 32, cb + boff1);
        }
        if (ks <= 28) vm_wait4();            // retire B(ks+1); keep A(ks+3)+B(ks+2)
        else if (ks == 29) vm_wait2();
        else if (ks == 30) vm_wait0();
        lgkm0();
        schedb();
        __builtin_amdgcn_s_barrier();
        schedb();
    };

    for (int kp = 0; kp < 16; ++kp) {
        body(2 * kp,     rA1x, rA2x, rA1y, rA2y);
        body(2 * kp + 1, rA1y, rA2y, rA1x, rA2x);
    }
    __syncthreads();

    // gcn-gate: full-row dot from acc regs
    float wgv[4];
    #pragma unroll
    for (int nt = 0; nt < 4; ++nt) wgv[nt] = Wg[wc * 64 + nt * 16 + mrow];
    #pragma unroll
    for (int mt = 0; mt < 4; ++mt) {
        #pragma unroll
        for (int rr = 0; rr < 4; ++rr) {
            float p = acc[mt][0][rr] * wgv[0] + acc[mt][1][rr] * wgv[1]
                    + acc[mt][2][rr] * wgv[2] + acc[mt][3][rr] * wgv[3];
            p += __shfl_xor(p, 1, 16);
            p += __shfl_xor(p, 2, 16);
            p += __shfl_xor(p, 4, 16);
            p += __shfl_xor(p, 8, 16);
            if (mrow == 0) psum[(wr * 64 + mt * 16 + hi * 4 + rr) * 4 + wc] = p;
        }
    }
    __syncthreads();
    if (t < 128) {
        const float d = psum[t * 4] + psum[t * 4 + 1] + psum[t * 4 + 2] + psum[t * 4 + 3];
        sh_s[t] = 1.f / (1.f + expf(-d));
    }
    __syncthreads();

    // 4 store passes of 32 rows each
    #pragma unroll
    for (int p = 0; p < 4; ++p) {
        if (wr == (p >> 1)) {
            #pragma unroll
            for (int mtl = 0; mtl < 2; ++mtl) {
                const int mt = (p & 1) * 2 + mtl;
                #pragma unroll
                for (int nt = 0; nt < 4; ++nt) {
                    const int col = wc * 64 + nt * 16 + mrow;
                    #pragma unroll
                    for (int rr = 0; rr < 4; ++rr) {
                        const int hrow = mtl * 16 + hi * 4 + rr;
                        hbuf[hrow * 260 + col] = acc[mt][nt][rr];
                    }
                }
            }
        }
        __syncthreads();
        {
            const int sr = t >> 4;
            const int sc0 = (t & 15) * 16;
            const int grow = p * 32 + sr;
            const float s = sh_s[grow];
            const size_t gb = ((size_t)b * N_ + m0 + grow) * D_ + sc0;
            const float* xr = xcur + gb;
            u16* orow = outp + gb;
            bf16x8 o0, o1;
            #pragma unroll
            for (int u = 0; u < 8; ++u)
                o0[u] = (short)f2bf(hbuf[sr * 260 + sc0 + u] * s + bg0 + xr[u]);
            #pragma unroll
            for (int u = 0; u < 8; ++u)
                o1[u] = (short)f2bf(hbuf[sr * 260 + sc0 + 8 + u] * s + bg0 + xr[8 + u]);
            *(bf16x8*)orow = o0;
            *(bf16x8*)(orow + 8) = o1;
        }
        __syncthreads();
    }
}

// ---------------------------------------------------------------------------
// K4: gemm-skeleton fc_ln (round-8 core). Tile 64m x 256n, 8 waves, grid 256.
// FUSE=1 (layer 0): additionally computes next layer's refine gate (row dot
// with rgN from registers/hbuf) and emits bf16 transposed xT for the next
// gemm's B — eliminating the layer-1 k_gate_xt launch and its 64MB re-read.
// Transpose phase reads hbuf column-wise: stride 260 f32 => all 32 banks hit,
// 2-lane pairs broadcast (free).
template<int FUSE>
__global__ __launch_bounds__(512, 2) void k_fc_ln(
    const u16* __restrict__ axin, const u16* __restrict__ axout,
    const u16* __restrict__ Wib, const u16* __restrict__ Wob,
    const float* __restrict__ bi, const float* __restrict__ bo,
    const float* __restrict__ lg, const float* __restrict__ lb,
    float* __restrict__ outp,
    const float* __restrict__ rgN, float* __restrict__ gateN,
    u16* __restrict__ xTN)
{
    __shared__ __align__(16) char smem[51712];
    u16* const sb = (u16*)smem;
    float* hbuf = (float*)smem;
    float* psum = (float*)(smem + 49152);
    float* sh_mu = (float*)(smem + 51200);
    float* sh_rs = (float*)(smem + 51456);

    const int bid = blockIdx.x;
    const int logical = (bid & 7) * 32 + (bid >> 3);
    const int b = logical >> 4;
    const int m0 = (logical & 15) * 64;

    const int t = threadIdx.x, lane = t & 63, w = t >> 6;
    const int wr = w >> 2, wc = w & 3;
    const int half = wc >> 1;

    const int rl = lane >> 2;
    const int kk = (((lane & 3) ^ ((lane >> 3) & 3)) << 3);

    const u16* gsrc[3];
    int loff[3];
    #pragma unroll
    for (int ci = 0; ci < 3; ++ci) {
        const int c = w * 3 + ci;
        if (c < 4) {
            gsrc[ci] = axin + ((size_t)b * N_ + m0 + c * 16 + rl) * D_ + kk;
            loff[ci] = c * 512;
        } else if (c < 8) {
            gsrc[ci] = axout + ((size_t)b * N_ + m0 + (c - 4) * 16 + rl) * D_ + kk;
            loff[ci] = 2048 + (c - 4) * 512;
        } else {
            const int cw = c - 8;
            const u16* base = (cw < 8) ? (Wib + (size_t)(cw * 16 + rl) * D_)
                                       : (Wob + (size_t)((cw - 8) * 16 + rl) * D_);
            gsrc[ci] = base + kk;
            loff[ci] = 4096 + cw * 512;
        }
    }

    f32x4 acc[2][4];
    const f32x4 fz = {0.f, 0.f, 0.f, 0.f};
    #pragma unroll
    for (int i = 0; i < 2; ++i)
        #pragma unroll
        for (int j = 0; j < 4; ++j) acc[i][j] = fz;

    #pragma unroll
    for (int ci = 0; ci < 3; ++ci) gl_lds16(gsrc[ci], sb + loff[ci]);
    #pragma unroll
    for (int ci = 0; ci < 3; ++ci) gl_lds16(gsrc[ci] + 32, sb + 12288 + loff[ci]);
    vm_wait3();
    lgkm0();
    schedb(); __builtin_amdgcn_s_barrier(); schedb();

    const int mrow = lane & 15;
    const int hi = lane >> 4;
    const int kg = (((lane >> 4) ^ ((mrow >> 1) & 3)) << 3);

    for (int ks = 0; ks < 8; ++ks) {
        const u16* cur = sb + (ks & 1) * 12288;
        const u16* sA = cur + (half ? 2048 : 0);
        const u16* sW = cur + 4096;
        bf16x8 a[2], fbv[4];
        #pragma unroll
        for (int mt = 0; mt < 2; ++mt)
            a[mt] = *(const bf16x8*)(sA + (wr * 32 + mt * 16 + mrow) * 32 + kg);
        #pragma unroll
        for (int nt = 0; nt < 4; ++nt)
            fbv[nt] = *(const bf16x8*)(sW + (wc * 64 + nt * 16 + mrow) * 32 + kg);
        #pragma unroll
        for (int mt = 0; mt < 2; ++mt)
            #pragma unroll
            for (int nt = 0; nt < 4; ++nt)
                acc[mt][nt] = __builtin_amdgcn_mfma_f32_16x16x32_bf16(a[mt], fbv[nt], acc[mt][nt], 0, 0, 0);
        schedb();
        __builtin_amdgcn_s_barrier();
        schedb();
        if (ks <= 5) {
            u16* nb = sb + (ks & 1) * 12288;
            #pragma unroll
            for (int ci = 0; ci < 3; ++ci) gl_lds16(gsrc[ci] + (ks + 2) * 32, nb + loff[ci]);
        }
        if (ks <= 5) vm_wait3();
        else if (ks == 6) vm_wait0();
        lgkm0();
        schedb();
        __builtin_amdgcn_s_barrier();
        schedb();
    }
    __syncthreads();

    float bc[4];
    #pragma unroll
    for (int nt = 0; nt < 4; ++nt) {
        const int colh = wc * 64 + nt * 16 + mrow;
        bc[nt] = 2.f * (colh < 128 ? bi[colh] : bo[colh - 128]);
    }
    #pragma unroll
    for (int mt = 0; mt < 2; ++mt)
        #pragma unroll
        for (int rr = 0; rr < 4; ++rr) {
            const int lrow = wr * 32 + mt * 16 + hi * 4 + rr;
            float s = 0.f, ss = 0.f;
            #pragma unroll
            for (int nt = 0; nt < 4; ++nt) {
                const float v = acc[mt][nt][rr] + bc[nt];
                s += v; ss += v * v;
            }
            s += __shfl_xor(s, 1, 16);  ss += __shfl_xor(ss, 1, 16);
            s += __shfl_xor(s, 2, 16);  ss += __shfl_xor(ss, 2, 16);
            s += __shfl_xor(s, 4, 16);  ss += __shfl_xor(ss, 4, 16);
            s += __shfl_xor(s, 8, 16);  ss += __shfl_xor(ss, 8, 16);
            if (mrow == 0) {
                psum[lrow * 8 + wc * 2] = s;
                psum[lrow * 8 + wc * 2 + 1] = ss;
            }
        }
    __syncthreads();
    if (t < 64) {
        const float s = psum[t * 8] + psum[t * 8 + 2] + psum[t * 8 + 4] + psum[t * 8 + 6];
        const float ss = psum[t * 8 + 1] + psum[t * 8 + 3] + psum[t * 8 + 5] + psum[t * 8 + 7];
        const float mu = s * (1.f / 256.f);
        const float var = ss * (1.f / 256.f) - mu * mu;
        sh_mu[t] = mu;
        sh_rs[t] = rsqrtf(var + 1e-5f);
    }
    __syncthreads();

    #pragma unroll
    for (int p = 0; p < 2; ++p) {
        if (wr == p) {
            #pragma unroll
            for (int mt = 0; mt < 2; ++mt)
                #pragma unroll
                for (int nt = 0; nt < 4; ++nt) {
                    const int col = wc * 64 + nt * 16 + mrow;
                    #pragma unroll
                    for (int rr = 0; rr < 4; ++rr) {
                        const int hrow = mt * 16 + hi * 4 + rr;
                        hbuf[hrow * 260 + col] = acc[mt][nt][rr] + bc[nt];
                    }
                }
        }
        __syncthreads();
        {
            const int sr = t >> 4;
            const int sc0 = (t & 15) * 16;
            const int grow = p * 32 + sr;
            const float mu = sh_mu[grow], rs = sh_rs[grow];
            float* orow = outp + ((size_t)b * N_ + m0 + grow) * D_ + sc0;
            float gdot = 0.f;
            #pragma unroll
            for (int q = 0; q < 4; ++q) {
                const float4 gg = *(const float4*)(lg + sc0 + q * 4);
                const float4 bb = *(const float4*)(lb + sc0 + q * 4);
                float4 o;
                const float v0 = (hbuf[sr * 260 + sc0 + q * 4    ] - mu) * rs * gg.x + bb.x;
                const float v1 = (hbuf[sr * 260 + sc0 + q * 4 + 1] - mu) * rs * gg.y + bb.y;
                const float v2 = (hbuf[sr * 260 + sc0 + q * 4 + 2] - mu) * rs * gg.z + bb.z;
                const float v3 = (hbuf[sr * 260 + sc0 + q * 4 + 3] - mu) * rs * gg.w + bb.w;
                o.x = 0.5f * v0 * (1.f + erff(v0 * 0.70710678118654752f));
                o.y = 0.5f * v1 * (1.f + erff(v1 * 0.70710678118654752f));
                o.z = 0.5f * v2 * (1.f + erff(v2 * 0.70710678118654752f));
                o.w = 0.5f * v3 * (1.f + erff(v3 * 0.70710678118654752f));
                *(float4*)(orow + q * 4) = o;
                if (FUSE) {
                    // write y back to hbuf for the transpose phase + gate dot
                    hbuf[sr * 260 + sc0 + q * 4    ] = o.x;
                    hbuf[sr * 260 + sc0 + q * 4 + 1] = o.y;
                    hbuf[sr * 260 + sc0 + q * 4 + 2] = o.z;
                    hbuf[sr * 260 + sc0 + q * 4 + 3] = o.w;
                    const float4 rv = *(const float4*)(rgN + sc0 + q * 4);
                    gdot += o.x * rv.x + o.y * rv.y + o.z * rv.z + o.w * rv.w;
                }
            }
            if (FUSE) {
                gdot += __shfl_xor(gdot, 1, 16);
                gdot += __shfl_xor(gdot, 2, 16);
                gdot += __shfl_xor(gdot, 4, 16);
                gdot += __shfl_xor(gdot, 8, 16);
                if ((t & 15) == 0)
                    gateN[(size_t)b * N_ + m0 + grow] = 1.f / (1.f + expf(-gdot));
            }
        }
        __syncthreads();
        if (FUSE) {
            // transpose phase: thread t -> d = t>>1, n-half = (t&1)*16.
            // hbuf column read: word = (nh+i)*260 + d -> banks 4i+d, d spans
            // 32 consecutive per wave => conflict-free (pairs broadcast).
            const int d = t >> 1;
            const int nh = (t & 1) * 16;
            bf16x8 y0, y1;
            #pragma unroll
            for (int i = 0; i < 8; ++i)
                y0[i] = (short)f2bf(hbuf[(nh + i) * 260 + d]);
            #pragma unroll
            for (int i = 0; i < 8; ++i)
                y1[i] = (short)f2bf(hbuf[(nh + 8 + i) * 260 + d]);
            u16* xrow = xTN + ((size_t)b * D_ + d) * N_ + m0 + p * 32 + nh;
            *(bf16x8*)xrow = y0;
            *(bf16x8*)(xrow + 8) = y1;
            __syncthreads();
        }
    }
}

// ---------------------------------------------------------------------------
extern "C" void kernel_launch(void* const* d_in, const int* in_sizes, int n_in,
                              void* d_out, int out_size, void* d_ws, size_t ws_size,
                              hipStream_t stream)
{
    (void)in_sizes; (void)n_in; (void)out_size; (void)ws_size;

    const float* x0  = (const float*)d_in[0];
    const float* lat = (const float*)d_in[1];
    const float* dep = (const float*)d_in[2];
    const float* rg  = (const float*)d_in[3];
    const float* Wgi = (const float*)d_in[4];
    const float* bgi = (const float*)d_in[5];
    const float* Wgo = (const float*)d_in[6];
    const float* bgo = (const float*)d_in[7];
    const float* fiW = (const float*)d_in[8];
    const float* fib = (const float*)d_in[9];
    const float* foW = (const float*)d_in[10];
    const float* fob = (const float*)d_in[11];
    const float* lng = (const float*)d_in[12];
    const float* lnb = (const float*)d_in[13];

    char* ws = (char*)d_ws;
    size_t off = 0;
    auto alloc = [&](size_t bytes) {
        char* p = ws + off;
        off += (bytes + 255) & ~(size_t)255;
        return p;
    };
    u16* depb  = (u16*)alloc(2ull * B_ * N_ * N_);
    u16* latb  = (u16*)alloc(2ull * B_ * N_ * N_);
    u16* depTb = (u16*)alloc(2ull * B_ * N_ * N_);
    u16* latTb = (u16*)alloc(2ull * B_ * N_ * N_);
    u16* xT    = (u16*)alloc(2ull * B_ * D_ * N_);
    u16* axin  = (u16*)alloc(2ull * B_ * N_ * D_);
    u16* axout = (u16*)alloc(2ull * B_ * N_ * D_);
    float* gate = (float*)alloc(4ull * B_ * N_);
    float* xbuf = (float*)alloc(4ull * B_ * N_ * D_);
    u16* Wib = (u16*)alloc(2ull * 2 * H_ * D_);   // both layers
    u16* Wob = (u16*)alloc(2ull * 2 * H_ * D_);

    k_conv_adj<<<dim3(16, 16, 32), 256, 0, stream>>>(dep, lat, depb, latb, depTb, latTb);

    // layer 0 gate + x0 transpose; extra slices convert BOTH layers' weights
    k_gate_xt<<<dim3(32, B_ + 8), 256, 0, stream>>>(
        x0, rg, gate, xT, fiW, foW, Wib, Wob);

    // layer 0
    k_gemm_ax<<<dim3(256), 512, 0, stream>>>(
        depb, latb, depTb, latTb, xT, gate,
        Wgi, Wgo, bgi, bgo, x0, axin, axout);
    // fused: writes xbuf + layer-1 gate + layer-1 xT
    k_fc_ln<1><<<dim3(256), 512, 0, stream>>>(
        axin, axout, Wib, Wob, fib, fob, lng, lnb,
        xbuf, rg + D_, gate, xT);

    // layer 1
    k_gemm_ax<<<dim3(256), 512, 0, stream>>>(
        depb, latb, depTb, latTb, xT, gate,
        Wgi + D_, Wgo + D_, bgi + 1, bgo + 1, xbuf, axin, axout);
    k_fc_ln<0><<<dim3(256), 512, 0, stream>>>(
        axin, axout, Wib + (size_t)H_ * D_, Wob + (size_t)H_ * D_,
        fib + H_, fob + H_, lng + 2 * H_, lnb + 2 * H_,
        (float*)d_out, nullptr, nullptr, nullptr);
}